// Round 14
// baseline (341.403 us; speedup 1.0000x reference)
//
#include <hip/hip_runtime.h>

#define CDIM 256
#define NDET 900
#define NMAP 100
#define NPTS 20
#define NBLK 1000

// packed layouts in ws: [cam][H*W][C]
#define P4OFF 7372800    // after p3T (6*4800*256)
#define P5OFF 9216000    // after p4T (6*1200*256)
#define CNTOFF 9292800   // u32 barrier counter (float index)
#define C3STR 1228800    // 4800*256
#define C4STR 307200     // 1200*256
#define C5STR 76800      // 300*256

__global__ __launch_bounds__(256, 4) void autonav_fused(
    const float* __restrict__ p2, const float* __restrict__ p3,
    const float* __restrict__ p4, const float* __restrict__ p5,
    const float* __restrict__ Kin, const float* __restrict__ Ein,
    const float* __restrict__ det3d, const float* __restrict__ detfull,
    const float* __restrict__ mapanch,
    const float* __restrict__ W1d, const float* __restrict__ b1d,
    const float* __restrict__ Wcd, const float* __restrict__ bcd,
    const float* __restrict__ Wod, const float* __restrict__ bod,
    const float* __restrict__ W1m, const float* __restrict__ b1m,
    const float* __restrict__ Wcm, const float* __restrict__ bcm,
    const float* __restrict__ Wom, const float* __restrict__ bom,
    float* __restrict__ wsf, unsigned int* __restrict__ cnt,
    float* __restrict__ out)
{
    const int b = blockIdx.x;       // == point id
    const int t = threadIdx.x;
    const bool isDet = (b < NDET);
    const int m = b - NDET;
    const int pt = b;

    __shared__ float s_tile[64][65];     // p3 transpose buffer
    __shared__ int   s_off0[7][4];       // phase A: p2 tiles
    __shared__ float s_w0[7][4];
    __shared__ int   s_list0[8];
    __shared__ int   s_n0;
    __shared__ int   s_off[19][4];       // phase B: lvl1-3 tiles
    __shared__ float s_w[19][4];
    __shared__ int   s_list[24];
    __shared__ int   s_n;
    __shared__ float s_vec[CDIM];
    __shared__ float s_hid[CDIM];

    // ================= Phase A1: level-0 (p2) gather, acc in register =========
    if (t < 7) {
        float h0, h1, h2;
        if (isDet) {
            h0 = det3d[pt * 3 + 0];
            h1 = det3d[pt * 3 + 1];
            h2 = det3d[pt * 3 + 2];
        } else {
            float cx = 0.f, cy = 0.f;
            #pragma unroll
            for (int j = 0; j < NPTS; ++j) {
                cx += mapanch[(m * NPTS + j) * 2 + 0];
                cy += mapanch[(m * NPTS + j) * 2 + 1];
            }
            h0 = cx / (float)NPTS; h1 = cy / (float)NPTS; h2 = 0.f;
        }
        bool pred = false;
        if (t < 6) {
            const int cam = t;
            float pc[3];
            #pragma unroll
            for (int i = 0; i < 3; ++i) {
                pc[i] = Ein[cam * 16 + i * 4 + 0] * h0
                      + Ein[cam * 16 + i * 4 + 1] * h1
                      + Ein[cam * 16 + i * 4 + 2] * h2
                      + Ein[cam * 16 + i * 4 + 3] * 1.f;
            }
            const float q0 = Kin[cam*9+0]*pc[0] + Kin[cam*9+1]*pc[1] + Kin[cam*9+2]*pc[2];
            const float q1 = Kin[cam*9+3]*pc[0] + Kin[cam*9+4]*pc[1] + Kin[cam*9+5]*pc[2];
            const float q2 = Kin[cam*9+6]*pc[0] + Kin[cam*9+7]*pc[1] + Kin[cam*9+8]*pc[2];
            const float depth = q2;
            const float u = q0 / (depth + 1e-6f);
            const float v = q1 / (depth + 1e-6f);
            const bool valid = (depth > 0.1f);
            const float gx = u / 640.0f * 2.0f - 1.0f;
            const float gy = v / 480.0f * 2.0f - 1.0f;
            const int H = 120, W = 160;
            const float x = (gx + 1.f) * (W * 0.5f) - 0.5f;
            const float y = (gy + 1.f) * (H * 0.5f) - 0.5f;
            const float x0f = floorf(x), y0f = floorf(y);
            const float wx1 = x - x0f, wx0 = 1.f - wx1;
            const float wy1 = y - y0f, wy0 = 1.f - wy1;
            const float x1f = x0f + 1.f, y1f = y0f + 1.f;
            const bool bx0 = (x0f >= 0.f) && (x0f <= (float)(W - 1));
            const bool bx1 = (x1f >= 0.f) && (x1f <= (float)(W - 1));
            const bool by0 = (y0f >= 0.f) && (y0f <= (float)(H - 1));
            const bool by1 = (y1f >= 0.f) && (y1f <= (float)(H - 1));
            const int xc0 = (int)fminf(fmaxf(x0f, 0.f), (float)(W - 1));
            const int xc1 = (int)fminf(fmaxf(x1f, 0.f), (float)(W - 1));
            const int yc0 = (int)fminf(fmaxf(y0f, 0.f), (float)(H - 1));
            const int yc1 = (int)fminf(fmaxf(y1f, 0.f), (float)(H - 1));
            const int base = cam * CDIM * H * W;
            s_off0[t][0] = base + yc0 * W + xc0;
            s_off0[t][1] = base + yc0 * W + xc1;
            s_off0[t][2] = base + yc1 * W + xc0;
            s_off0[t][3] = base + yc1 * W + xc1;
            const float w0 = (bx0 && by0) ? wx0 * wy0 : 0.f;
            const float w1 = (bx1 && by0) ? wx1 * wy0 : 0.f;
            const float w2 = (bx0 && by1) ? wx0 * wy1 : 0.f;
            const float w3 = (bx1 && by1) ? wx1 * wy1 : 0.f;
            s_w0[t][0] = w0; s_w0[t][1] = w1; s_w0[t][2] = w2; s_w0[t][3] = w3;
            pred = valid && ((w0 + w1 + w2 + w3) != 0.f);
        } else {
            s_off0[6][0] = 0; s_off0[6][1] = 0; s_off0[6][2] = 0; s_off0[6][3] = 0;
            s_w0[6][0] = 0.f; s_w0[6][1] = 0.f; s_w0[6][2] = 0.f; s_w0[6][3] = 0.f;
        }
        const unsigned long long mask = __ballot(pred);
        const int n = __popcll(mask);
        const int rank = __popcll(mask & ((1ull << t) - 1ull));
        if (pred) s_list0[rank] = t;
        const int npad = (n + 1) & ~1;
        if (t < 2 && (n + t) < npad) s_list0[n + t] = 6;
        if (t == 0) s_n0 = npad;
    }
    __syncthreads();

    float acc = 0.f;
    {
        const int npad0 = s_n0;
        const int cHW = t * 19200;
        for (int base = 0; base < npad0; base += 2) {
            float v[2][4];
            int tj[2];
            #pragma unroll
            for (int j = 0; j < 2; ++j) {
                const int tt = s_list0[base + j];
                tj[j] = tt;
                v[j][0] = p2[s_off0[tt][0] + cHW];
                v[j][1] = p2[s_off0[tt][1] + cHW];
                v[j][2] = p2[s_off0[tt][2] + cHW];
                v[j][3] = p2[s_off0[tt][3] + cHW];
            }
            #pragma unroll
            for (int j = 0; j < 2; ++j) {
                const int tt = tj[j];
                acc += s_w0[tt][0] * v[j][0] + s_w0[tt][1] * v[j][1]
                     + s_w0[tt][2] * v[j][2] + s_w0[tt][3] * v[j][3];
            }
        }
    }

    // ================= Phase A2: pack units (p3 LDS-transpose, p4/p5 rows) =====
    const int lane = t & 63;
    const int wv = t >> 6;
    for (int u = 1000 + b; u < 3070; u += 1000) {
        const int pu = u - 1000;
        __syncthreads();   // protect s_tile reuse
        if (pu < 1800) {
            // p3 transpose tile: 64 px x 64 ch, coalesced both sides
            const int cam = pu / 300;
            const int rem = pu % 300;
            const int pxT = rem / 4, chT = rem % 4;
            #pragma unroll
            for (int cc = 0; cc < 16; ++cc) {
                const int chl = wv * 16 + cc;
                s_tile[chl][lane] = p3[(cam * CDIM + chT * 64 + chl) * 4800 + pxT * 64 + lane];
            }
            __syncthreads();
            #pragma unroll
            for (int pp = 0; pp < 16; ++pp) {
                const int pxl = wv * 16 + pp;
                wsf[(cam * 4800 + pxT * 64 + pxl) * CDIM + chT * 64 + lane] = s_tile[lane][pxl];
            }
        } else if (pu < 1980) {
            const int id = pu - 1800;
            const int cam = id / 30, h = id % 30;
            const float4* __restrict__ src = (const float4*)(p4 + ((cam * CDIM + t) * 30 + h) * 40);
            float* __restrict__ dst = wsf + P4OFF + ((cam * 30 + h) * 40) * CDIM + t;
            #pragma unroll
            for (int w4 = 0; w4 < 10; ++w4) {
                const float4 v = src[w4];
                dst[(w4 * 4 + 0) * CDIM] = v.x;
                dst[(w4 * 4 + 1) * CDIM] = v.y;
                dst[(w4 * 4 + 2) * CDIM] = v.z;
                dst[(w4 * 4 + 3) * CDIM] = v.w;
            }
        } else {
            const int id = pu - 1980;
            const int cam = id / 15, h = id % 15;
            const float4* __restrict__ src = (const float4*)(p5 + ((cam * CDIM + t) * 15 + h) * 20);
            float* __restrict__ dst = wsf + P5OFF + ((cam * 15 + h) * 20) * CDIM + t;
            #pragma unroll
            for (int w4 = 0; w4 < 5; ++w4) {
                const float4 v = src[w4];
                dst[(w4 * 4 + 0) * CDIM] = v.x;
                dst[(w4 * 4 + 1) * CDIM] = v.y;
                dst[(w4 * 4 + 2) * CDIM] = v.z;
                dst[(w4 * 4 + 3) * CDIM] = v.w;
            }
        }
    }

    // ================= Grid barrier (all 1000 blocks co-resident) =============
    __threadfence();           // push pack writes to agent scope
    __syncthreads();
    if (t == 0) {
        __hip_atomic_fetch_add(cnt, 1u, __ATOMIC_RELEASE, __HIP_MEMORY_SCOPE_AGENT);
        int guard = 0;
        while (__hip_atomic_load(cnt, __ATOMIC_ACQUIRE, __HIP_MEMORY_SCOPE_AGENT) < (unsigned)NBLK) {
            __builtin_amdgcn_s_sleep(2);
            if (++guard > (1 << 27)) break;   // hang insurance; never triggers when co-resident
        }
    }
    __syncthreads();
    __threadfence();

    // ================= Phase B: levels 1-3 coalesced gather + MLP + heads =====
    if (t < 19) {
        float h0, h1, h2;
        if (isDet) {
            h0 = det3d[pt * 3 + 0];
            h1 = det3d[pt * 3 + 1];
            h2 = det3d[pt * 3 + 2];
        } else {
            float cx = 0.f, cy = 0.f;
            #pragma unroll
            for (int j = 0; j < NPTS; ++j) {
                cx += mapanch[(m * NPTS + j) * 2 + 0];
                cy += mapanch[(m * NPTS + j) * 2 + 1];
            }
            h0 = cx / (float)NPTS; h1 = cy / (float)NPTS; h2 = 0.f;
        }
        bool pred = false;
        if (t < 18) {
            const int cam = t / 3, l = 1 + (t % 3);
            float pc[3];
            #pragma unroll
            for (int i = 0; i < 3; ++i) {
                pc[i] = Ein[cam * 16 + i * 4 + 0] * h0
                      + Ein[cam * 16 + i * 4 + 1] * h1
                      + Ein[cam * 16 + i * 4 + 2] * h2
                      + Ein[cam * 16 + i * 4 + 3] * 1.f;
            }
            const float q0 = Kin[cam*9+0]*pc[0] + Kin[cam*9+1]*pc[1] + Kin[cam*9+2]*pc[2];
            const float q1 = Kin[cam*9+3]*pc[0] + Kin[cam*9+4]*pc[1] + Kin[cam*9+5]*pc[2];
            const float q2 = Kin[cam*9+6]*pc[0] + Kin[cam*9+7]*pc[1] + Kin[cam*9+8]*pc[2];
            const float depth = q2;
            const float u = q0 / (depth + 1e-6f);
            const float v = q1 / (depth + 1e-6f);
            const bool valid = (depth > 0.1f);
            const float gx = u / 640.0f * 2.0f - 1.0f;
            const float gy = v / 480.0f * 2.0f - 1.0f;
            const int Hs[4] = {120, 60, 30, 15};
            const int Ws[4] = {160, 80, 40, 20};
            const int H = Hs[l], W = Ws[l];
            const float x = (gx + 1.f) * (W * 0.5f) - 0.5f;
            const float y = (gy + 1.f) * (H * 0.5f) - 0.5f;
            const float x0f = floorf(x), y0f = floorf(y);
            const float wx1 = x - x0f, wx0 = 1.f - wx1;
            const float wy1 = y - y0f, wy0 = 1.f - wy1;
            const float x1f = x0f + 1.f, y1f = y0f + 1.f;
            const bool bx0 = (x0f >= 0.f) && (x0f <= (float)(W - 1));
            const bool bx1 = (x1f >= 0.f) && (x1f <= (float)(W - 1));
            const bool by0 = (y0f >= 0.f) && (y0f <= (float)(H - 1));
            const bool by1 = (y1f >= 0.f) && (y1f <= (float)(H - 1));
            const int xc0 = (int)fminf(fmaxf(x0f, 0.f), (float)(W - 1));
            const int xc1 = (int)fminf(fmaxf(x1f, 0.f), (float)(W - 1));
            const int yc0 = (int)fminf(fmaxf(y0f, 0.f), (float)(H - 1));
            const int yc1 = (int)fminf(fmaxf(y1f, 0.f), (float)(H - 1));
            const int pb = (l == 1) ? cam * C3STR
                         : (l == 2) ? (P4OFF + cam * C4STR)
                                    : (P5OFF + cam * C5STR);
            s_off[t][0] = pb + (yc0 * W + xc0) * CDIM;
            s_off[t][1] = pb + (yc0 * W + xc1) * CDIM;
            s_off[t][2] = pb + (yc1 * W + xc0) * CDIM;
            s_off[t][3] = pb + (yc1 * W + xc1) * CDIM;
            const float w0 = (bx0 && by0) ? wx0 * wy0 : 0.f;
            const float w1 = (bx1 && by0) ? wx1 * wy0 : 0.f;
            const float w2 = (bx0 && by1) ? wx0 * wy1 : 0.f;
            const float w3 = (bx1 && by1) ? wx1 * wy1 : 0.f;
            s_w[t][0] = w0; s_w[t][1] = w1; s_w[t][2] = w2; s_w[t][3] = w3;
            pred = valid && ((w0 + w1 + w2 + w3) != 0.f);
        } else {
            s_off[18][0] = 0; s_off[18][1] = 0; s_off[18][2] = 0; s_off[18][3] = 0;
            s_w[18][0] = 0.f; s_w[18][1] = 0.f; s_w[18][2] = 0.f; s_w[18][3] = 0.f;
        }
        const unsigned long long mask = __ballot(pred);
        const int n = __popcll(mask);
        const int rank = __popcll(mask & ((1ull << t) - 1ull));
        if (pred) s_list[rank] = t;
        const int npad = (n + 7) & ~7;
        if (t < 8 && (n + t) < npad) s_list[n + t] = 18;
        if (t == 0) s_n = npad;
    }
    __syncthreads();

    const int npad = s_n;
    for (int base = 0; base < npad; base += 8) {
        float v[8][4];
        int tj[8];
        #pragma unroll
        for (int j = 0; j < 8; ++j) {
            const int tt = s_list[base + j];
            tj[j] = tt;
            v[j][0] = wsf[s_off[tt][0] + t];
            v[j][1] = wsf[s_off[tt][1] + t];
            v[j][2] = wsf[s_off[tt][2] + t];
            v[j][3] = wsf[s_off[tt][3] + t];
        }
        #pragma unroll
        for (int j = 0; j < 8; ++j) {
            const int tt = tj[j];
            acc += s_w[tt][0] * v[j][0] + s_w[tt][1] * v[j][1]
                 + s_w[tt][2] * v[j][2] + s_w[tt][3] * v[j][3];
        }
    }
    const float agg = (acc * 0.25f) / 6.0f;

    s_vec[t] = agg;
    __syncthreads();

    const float* __restrict__ W1 = isDet ? W1d : W1m;
    const float* __restrict__ b1 = isDet ? b1d : b1m;
    float hsum = b1[t];
    const float4* sv4 = (const float4*)s_vec;
    float wvA[32], wvB[32];
    #pragma unroll
    for (int i = 0; i < 32; ++i) wvA[i] = W1[i * CDIM + t];
    #pragma unroll
    for (int k0 = 0; k0 < CDIM; k0 += 64) {
        #pragma unroll
        for (int i = 0; i < 32; ++i) wvB[i] = W1[(k0 + 32 + i) * CDIM + t];
        #pragma unroll
        for (int i = 0; i < 8; ++i) {
            const float4 x = sv4[(k0 >> 2) + i];
            hsum = fmaf(x.x, wvA[4 * i + 0], hsum);
            hsum = fmaf(x.y, wvA[4 * i + 1], hsum);
            hsum = fmaf(x.z, wvA[4 * i + 2], hsum);
            hsum = fmaf(x.w, wvA[4 * i + 3], hsum);
        }
        if (k0 + 64 < CDIM) {
            #pragma unroll
            for (int i = 0; i < 32; ++i) wvA[i] = W1[(k0 + 64 + i) * CDIM + t];
        }
        #pragma unroll
        for (int i = 0; i < 8; ++i) {
            const float4 x = sv4[(k0 >> 2) + 8 + i];
            hsum = fmaf(x.x, wvB[4 * i + 0], hsum);
            hsum = fmaf(x.y, wvB[4 * i + 1], hsum);
            hsum = fmaf(x.z, wvB[4 * i + 2], hsum);
            hsum = fmaf(x.w, wvB[4 * i + 3], hsum);
        }
    }
    s_hid[t] = fmaxf(hsum, 0.f);
    __syncthreads();

    const int g  = t >> 4;
    const int ln = t & 15;
    const int nOut = isDet ? 15 : 43;
    const int nrep = isDet ? 1 : 3;
    for (int rep = 0; rep < nrep; ++rep) {
        const int o = g + rep * 16;
        if (o < nOut) {
            const float* Wp; int stride, oo, ooff; float bias;
            if (isDet) {
                if (o < 4) { Wp = Wcd; stride = 4;  oo = o;     ooff = pt * 4 + oo;         bias = bcd[oo]; }
                else       { Wp = Wod; stride = 11; oo = o - 4; ooff = 3600 + pt * 11 + oo; bias = bod[oo] + detfull[pt * 11 + oo]; }
            } else {
                if (o < 3) { Wp = Wcm; stride = 3;  oo = o;     ooff = 13500 + m * 3 + oo;  bias = bcm[oo]; }
                else       { Wp = Wom; stride = 40; oo = o - 3; ooff = 13800 + m * 40 + oo; bias = bom[oo] + mapanch[m * 40 + oo]; }
            }
            float wvh[16], xvh[16];
            #pragma unroll
            for (int kk = 0; kk < 16; ++kk) wvh[kk] = Wp[(ln + kk * 16) * stride + oo];
            #pragma unroll
            for (int kk = 0; kk < 16; ++kk) xvh[kk] = s_hid[ln + kk * 16];
            float sp = 0.f;
            #pragma unroll
            for (int kk = 0; kk < 16; ++kk) sp = fmaf(xvh[kk], wvh[kk], sp);
            #pragma unroll
            for (int off = 1; off < 16; off <<= 1) sp += __shfl_xor(sp, off, 64);
            if (ln == 0) out[ooff] = sp + bias;
        }
    }
}

extern "C" void kernel_launch(void* const* d_in, const int* in_sizes, int n_in,
                              void* d_out, int out_size, void* d_ws, size_t ws_size,
                              hipStream_t stream) {
    const float* p2      = (const float*)d_in[0];
    const float* p3      = (const float*)d_in[1];
    const float* p4      = (const float*)d_in[2];
    const float* p5      = (const float*)d_in[3];
    const float* Kin     = (const float*)d_in[4];
    const float* Ein     = (const float*)d_in[5];
    const float* det3d   = (const float*)d_in[6];
    const float* detfull = (const float*)d_in[7];
    const float* mapanch = (const float*)d_in[8];
    const float* W1d     = (const float*)d_in[9];
    const float* b1d     = (const float*)d_in[10];
    const float* Wcd     = (const float*)d_in[11];
    const float* bcd     = (const float*)d_in[12];
    const float* Wod     = (const float*)d_in[13];
    const float* bod     = (const float*)d_in[14];
    const float* W1m     = (const float*)d_in[15];
    const float* b1m     = (const float*)d_in[16];
    const float* Wcm     = (const float*)d_in[17];
    const float* bcm     = (const float*)d_in[18];
    const float* Wom     = (const float*)d_in[19];
    const float* bom     = (const float*)d_in[20];
    float* out = (float*)d_out;
    float* wsf = (float*)d_ws;
    unsigned int* cnt = (unsigned int*)(wsf + CNTOFF);

    // reset barrier counter (ws state persists across replays)
    hipMemsetAsync(cnt, 0, sizeof(unsigned int), stream);

    autonav_fused<<<NBLK, 256, 0, stream>>>(
        p2, p3, p4, p5, Kin, Ein, det3d, detfull, mapanch,
        W1d, b1d, Wcd, bcd, Wod, bod, W1m, b1m, Wcm, bcm, Wom, bom,
        wsf, cnt, out);
}

// Round 15
// 51.017 us; speedup vs baseline: 6.6919x; 6.6919x over previous
//
#include <hip/hip_runtime.h>

#define CDIM 256
#define NDET 900
#define NMAP 100
#define NPTS 20
#define NBLK (NDET + NMAP)

using u16 = unsigned short;

// packed bf16 layouts in ws ([cam][px][C], ushort units)
#define U4OFF 7372800    // after p3T (6*4800*256)
#define U5OFF 9216000    // after p4T (6*1200*256)
#define UEND  9676800
#define ACCF  4838400    // float index of acc region (== UEND ushorts / 2)
#define C3STR 1228800    // 4800*256
#define C4STR 307200     // 1200*256
#define C5STR 76800      // 300*256

__device__ __forceinline__ u16 f2bf(float f) {
    union { float f; unsigned int i; } v; v.f = f;
    return (u16)((v.i + 0x7FFFu + ((v.i >> 16) & 1u)) >> 16);
}
__device__ __forceinline__ float bf2f(u16 u) {
    union { unsigned int i; float f; } v; v.i = ((unsigned int)u) << 16; return v.f;
}

// ---------- K1: p3 LDS-transpose pack + p4/p5 row pack (bf16) + p2 gather ----------
__global__ __launch_bounds__(256, 4) void k1_pack_p2(
    const float* __restrict__ p2, const float* __restrict__ p3,
    const float* __restrict__ p4, const float* __restrict__ p5,
    const float* __restrict__ Kin, const float* __restrict__ Ein,
    const float* __restrict__ det3d, const float* __restrict__ mapanch,
    u16* __restrict__ wsb, float* __restrict__ accw)
{
    const int b = blockIdx.x;
    const int t = threadIdx.x;

    __shared__ float s_tile[64][65];

    if (b < 1800) {
        // ---- p3 transpose tile: 64 px x 64 ch, coalesced read AND write ----
        const int cam = b / 300;          // 75 pxT x 4 chT per cam
        const int rem = b % 300;
        const int pxT = rem >> 2, chT = rem & 3;
        const int lane = t & 63, wv = t >> 6;
        #pragma unroll
        for (int cc = 0; cc < 16; ++cc) {
            const int chl = wv * 16 + cc;
            s_tile[chl][lane] = p3[(cam * CDIM + chT * 64 + chl) * 4800 + pxT * 64 + lane];
        }
        __syncthreads();
        #pragma unroll
        for (int pp = 0; pp < 16; ++pp) {
            const int pxl = wv * 16 + pp;
            wsb[(cam * 4800 + pxT * 64 + pxl) * CDIM + chT * 64 + lane] = f2bf(s_tile[lane][pxl]);
        }
        return;
    }
    if (b < 1980) {
        const int id = b - 1800;
        const int cam = id / 30, h = id % 30;
        const float4* __restrict__ src = (const float4*)(p4 + ((cam * CDIM + t) * 30 + h) * 40);
        u16* __restrict__ dst = wsb + U4OFF + ((cam * 30 + h) * 40) * CDIM + t;
        #pragma unroll
        for (int w4 = 0; w4 < 10; ++w4) {
            const float4 v = src[w4];
            dst[(w4 * 4 + 0) * CDIM] = f2bf(v.x);
            dst[(w4 * 4 + 1) * CDIM] = f2bf(v.y);
            dst[(w4 * 4 + 2) * CDIM] = f2bf(v.z);
            dst[(w4 * 4 + 3) * CDIM] = f2bf(v.w);
        }
        return;
    }
    if (b < 2070) {
        const int id = b - 1980;
        const int cam = id / 15, h = id % 15;
        const float4* __restrict__ src = (const float4*)(p5 + ((cam * CDIM + t) * 15 + h) * 20);
        u16* __restrict__ dst = wsb + U5OFF + ((cam * 15 + h) * 20) * CDIM + t;
        #pragma unroll
        for (int w4 = 0; w4 < 5; ++w4) {
            const float4 v = src[w4];
            dst[(w4 * 4 + 0) * CDIM] = f2bf(v.x);
            dst[(w4 * 4 + 1) * CDIM] = f2bf(v.y);
            dst[(w4 * 4 + 2) * CDIM] = f2bf(v.z);
            dst[(w4 * 4 + 3) * CDIM] = f2bf(v.w);
        }
        return;
    }

    // ---- level-0 (p2) random gather for point pt ----
    const int pt = b - 2070;          // 0..999
    const bool isDet = (pt < NDET);
    const int m = pt - NDET;

    __shared__ int   s_off0[7][4];
    __shared__ float s_w0[7][4];
    __shared__ int   s_list0[8];
    __shared__ int   s_n0;

    if (t < 7) {
        float h0, h1, h2;
        if (isDet) {
            h0 = det3d[pt * 3 + 0];
            h1 = det3d[pt * 3 + 1];
            h2 = det3d[pt * 3 + 2];
        } else {
            float cx = 0.f, cy = 0.f;
            #pragma unroll
            for (int j = 0; j < NPTS; ++j) {
                cx += mapanch[(m * NPTS + j) * 2 + 0];
                cy += mapanch[(m * NPTS + j) * 2 + 1];
            }
            h0 = cx / (float)NPTS; h1 = cy / (float)NPTS; h2 = 0.f;
        }
        bool pred = false;
        if (t < 6) {
            const int cam = t;
            float pc[3];
            #pragma unroll
            for (int i = 0; i < 3; ++i) {
                pc[i] = Ein[cam * 16 + i * 4 + 0] * h0
                      + Ein[cam * 16 + i * 4 + 1] * h1
                      + Ein[cam * 16 + i * 4 + 2] * h2
                      + Ein[cam * 16 + i * 4 + 3] * 1.f;
            }
            const float q0 = Kin[cam*9+0]*pc[0] + Kin[cam*9+1]*pc[1] + Kin[cam*9+2]*pc[2];
            const float q1 = Kin[cam*9+3]*pc[0] + Kin[cam*9+4]*pc[1] + Kin[cam*9+5]*pc[2];
            const float q2 = Kin[cam*9+6]*pc[0] + Kin[cam*9+7]*pc[1] + Kin[cam*9+8]*pc[2];
            const float depth = q2;
            const float u = q0 / (depth + 1e-6f);
            const float v = q1 / (depth + 1e-6f);
            const bool valid = (depth > 0.1f);
            const float gx = u / 640.0f * 2.0f - 1.0f;
            const float gy = v / 480.0f * 2.0f - 1.0f;
            const int H = 120, W = 160;
            const float x = (gx + 1.f) * (W * 0.5f) - 0.5f;
            const float y = (gy + 1.f) * (H * 0.5f) - 0.5f;
            const float x0f = floorf(x), y0f = floorf(y);
            const float wx1 = x - x0f, wx0 = 1.f - wx1;
            const float wy1 = y - y0f, wy0 = 1.f - wy1;
            const float x1f = x0f + 1.f, y1f = y0f + 1.f;
            const bool bx0 = (x0f >= 0.f) && (x0f <= (float)(W - 1));
            const bool bx1 = (x1f >= 0.f) && (x1f <= (float)(W - 1));
            const bool by0 = (y0f >= 0.f) && (y0f <= (float)(H - 1));
            const bool by1 = (y1f >= 0.f) && (y1f <= (float)(H - 1));
            const int xc0 = (int)fminf(fmaxf(x0f, 0.f), (float)(W - 1));
            const int xc1 = (int)fminf(fmaxf(x1f, 0.f), (float)(W - 1));
            const int yc0 = (int)fminf(fmaxf(y0f, 0.f), (float)(H - 1));
            const int yc1 = (int)fminf(fmaxf(y1f, 0.f), (float)(H - 1));
            const int base = cam * CDIM * H * W;
            s_off0[t][0] = base + yc0 * W + xc0;
            s_off0[t][1] = base + yc0 * W + xc1;
            s_off0[t][2] = base + yc1 * W + xc0;
            s_off0[t][3] = base + yc1 * W + xc1;
            const float w0 = (bx0 && by0) ? wx0 * wy0 : 0.f;
            const float w1 = (bx1 && by0) ? wx1 * wy0 : 0.f;
            const float w2 = (bx0 && by1) ? wx0 * wy1 : 0.f;
            const float w3 = (bx1 && by1) ? wx1 * wy1 : 0.f;
            s_w0[t][0] = w0; s_w0[t][1] = w1; s_w0[t][2] = w2; s_w0[t][3] = w3;
            pred = valid && ((w0 + w1 + w2 + w3) != 0.f);
        } else {
            s_off0[6][0] = 0; s_off0[6][1] = 0; s_off0[6][2] = 0; s_off0[6][3] = 0;
            s_w0[6][0] = 0.f; s_w0[6][1] = 0.f; s_w0[6][2] = 0.f; s_w0[6][3] = 0.f;
        }
        const unsigned long long mask = __ballot(pred);
        const int n = __popcll(mask);
        const int rank = __popcll(mask & ((1ull << t) - 1ull));
        if (pred) s_list0[rank] = t;
        const int npad = (n + 1) & ~1;
        if (t < 2 && (n + t) < npad) s_list0[n + t] = 6;
        if (t == 0) s_n0 = npad;
    }
    __syncthreads();

    float acc = 0.f;
    const int npad = s_n0;
    const int cHW = t * 19200;
    for (int base = 0; base < npad; base += 2) {
        float v[2][4];
        int tj[2];
        #pragma unroll
        for (int j = 0; j < 2; ++j) {
            const int tt = s_list0[base + j];
            tj[j] = tt;
            v[j][0] = p2[s_off0[tt][0] + cHW];
            v[j][1] = p2[s_off0[tt][1] + cHW];
            v[j][2] = p2[s_off0[tt][2] + cHW];
            v[j][3] = p2[s_off0[tt][3] + cHW];
        }
        #pragma unroll
        for (int j = 0; j < 2; ++j) {
            const int tt = tj[j];
            acc += s_w0[tt][0] * v[j][0] + s_w0[tt][1] * v[j][1]
                 + s_w0[tt][2] * v[j][2] + s_w0[tt][3] * v[j][3];
        }
    }
    accw[pt * CDIM + t] = acc;
}

// ---------- K2: levels 1-3 coalesced bf16 gather + MLP + heads ----------
__global__ __launch_bounds__(256, 4) void k2_gather_mlp(
    const u16* __restrict__ wsb, const float* __restrict__ accw,
    const float* __restrict__ Kin, const float* __restrict__ Ein,
    const float* __restrict__ det3d, const float* __restrict__ detfull,
    const float* __restrict__ mapanch,
    const float* __restrict__ W1d, const float* __restrict__ b1d,
    const float* __restrict__ Wcd, const float* __restrict__ bcd,
    const float* __restrict__ Wod, const float* __restrict__ bod,
    const float* __restrict__ W1m, const float* __restrict__ b1m,
    const float* __restrict__ Wcm, const float* __restrict__ bcm,
    const float* __restrict__ Wom, const float* __restrict__ bom,
    float* __restrict__ out)
{
    const int pt = blockIdx.x;
    const int t  = threadIdx.x;
    const bool isDet = (pt < NDET);
    const int m = pt - NDET;

    __shared__ int   s_off[19][4];
    __shared__ float s_w[19][4];
    __shared__ int   s_list[24];
    __shared__ int   s_n;
    __shared__ float s_vec[CDIM];
    __shared__ float s_hid[CDIM];

    float acc = accw[pt * CDIM + t];

    if (t < 19) {
        float h0, h1, h2;
        if (isDet) {
            h0 = det3d[pt * 3 + 0];
            h1 = det3d[pt * 3 + 1];
            h2 = det3d[pt * 3 + 2];
        } else {
            float cx = 0.f, cy = 0.f;
            #pragma unroll
            for (int j = 0; j < NPTS; ++j) {
                cx += mapanch[(m * NPTS + j) * 2 + 0];
                cy += mapanch[(m * NPTS + j) * 2 + 1];
            }
            h0 = cx / (float)NPTS; h1 = cy / (float)NPTS; h2 = 0.f;
        }
        bool pred = false;
        if (t < 18) {
            const int cam = t / 3, l = 1 + (t % 3);
            float pc[3];
            #pragma unroll
            for (int i = 0; i < 3; ++i) {
                pc[i] = Ein[cam * 16 + i * 4 + 0] * h0
                      + Ein[cam * 16 + i * 4 + 1] * h1
                      + Ein[cam * 16 + i * 4 + 2] * h2
                      + Ein[cam * 16 + i * 4 + 3] * 1.f;
            }
            const float q0 = Kin[cam*9+0]*pc[0] + Kin[cam*9+1]*pc[1] + Kin[cam*9+2]*pc[2];
            const float q1 = Kin[cam*9+3]*pc[0] + Kin[cam*9+4]*pc[1] + Kin[cam*9+5]*pc[2];
            const float q2 = Kin[cam*9+6]*pc[0] + Kin[cam*9+7]*pc[1] + Kin[cam*9+8]*pc[2];
            const float depth = q2;
            const float u = q0 / (depth + 1e-6f);
            const float v = q1 / (depth + 1e-6f);
            const bool valid = (depth > 0.1f);
            const float gx = u / 640.0f * 2.0f - 1.0f;
            const float gy = v / 480.0f * 2.0f - 1.0f;
            const int Hs[4] = {120, 60, 30, 15};
            const int Ws[4] = {160, 80, 40, 20};
            const int H = Hs[l], W = Ws[l];
            const float x = (gx + 1.f) * (W * 0.5f) - 0.5f;
            const float y = (gy + 1.f) * (H * 0.5f) - 0.5f;
            const float x0f = floorf(x), y0f = floorf(y);
            const float wx1 = x - x0f, wx0 = 1.f - wx1;
            const float wy1 = y - y0f, wy0 = 1.f - wy1;
            const float x1f = x0f + 1.f, y1f = y0f + 1.f;
            const bool bx0 = (x0f >= 0.f) && (x0f <= (float)(W - 1));
            const bool bx1 = (x1f >= 0.f) && (x1f <= (float)(W - 1));
            const bool by0 = (y0f >= 0.f) && (y0f <= (float)(H - 1));
            const bool by1 = (y1f >= 0.f) && (y1f <= (float)(H - 1));
            const int xc0 = (int)fminf(fmaxf(x0f, 0.f), (float)(W - 1));
            const int xc1 = (int)fminf(fmaxf(x1f, 0.f), (float)(W - 1));
            const int yc0 = (int)fminf(fmaxf(y0f, 0.f), (float)(H - 1));
            const int yc1 = (int)fminf(fmaxf(y1f, 0.f), (float)(H - 1));
            const int pb = (l == 1) ? cam * C3STR
                         : (l == 2) ? (U4OFF + cam * C4STR)
                                    : (U5OFF + cam * C5STR);
            s_off[t][0] = pb + (yc0 * W + xc0) * CDIM;
            s_off[t][1] = pb + (yc0 * W + xc1) * CDIM;
            s_off[t][2] = pb + (yc1 * W + xc0) * CDIM;
            s_off[t][3] = pb + (yc1 * W + xc1) * CDIM;
            const float w0 = (bx0 && by0) ? wx0 * wy0 : 0.f;
            const float w1 = (bx1 && by0) ? wx1 * wy0 : 0.f;
            const float w2 = (bx0 && by1) ? wx0 * wy1 : 0.f;
            const float w3 = (bx1 && by1) ? wx1 * wy1 : 0.f;
            s_w[t][0] = w0; s_w[t][1] = w1; s_w[t][2] = w2; s_w[t][3] = w3;
            pred = valid && ((w0 + w1 + w2 + w3) != 0.f);
        } else {
            s_off[18][0] = 0; s_off[18][1] = 0; s_off[18][2] = 0; s_off[18][3] = 0;
            s_w[18][0] = 0.f; s_w[18][1] = 0.f; s_w[18][2] = 0.f; s_w[18][3] = 0.f;
        }
        const unsigned long long mask = __ballot(pred);
        const int n = __popcll(mask);
        const int rank = __popcll(mask & ((1ull << t) - 1ull));
        if (pred) s_list[rank] = t;
        const int npad = (n + 7) & ~7;
        if (t < 8 && (n + t) < npad) s_list[n + t] = 18;
        if (t == 0) s_n = npad;
    }
    __syncthreads();

    const int npad = s_n;
    for (int base = 0; base < npad; base += 8) {
        float v[8][4];
        int tj[8];
        #pragma unroll
        for (int j = 0; j < 8; ++j) {
            const int tt = s_list[base + j];
            tj[j] = tt;
            v[j][0] = bf2f(wsb[s_off[tt][0] + t]);
            v[j][1] = bf2f(wsb[s_off[tt][1] + t]);
            v[j][2] = bf2f(wsb[s_off[tt][2] + t]);
            v[j][3] = bf2f(wsb[s_off[tt][3] + t]);
        }
        #pragma unroll
        for (int j = 0; j < 8; ++j) {
            const int tt = tj[j];
            acc += s_w[tt][0] * v[j][0] + s_w[tt][1] * v[j][1]
                 + s_w[tt][2] * v[j][2] + s_w[tt][3] * v[j][3];
        }
    }
    const float agg = (acc * 0.25f) / 6.0f;

    s_vec[t] = agg;
    __syncthreads();

    const float* __restrict__ W1 = isDet ? W1d : W1m;
    const float* __restrict__ b1 = isDet ? b1d : b1m;
    float hsum = b1[t];
    const float4* sv4 = (const float4*)s_vec;
    float wvA[32], wvB[32];
    #pragma unroll
    for (int i = 0; i < 32; ++i) wvA[i] = W1[i * CDIM + t];
    #pragma unroll
    for (int k0 = 0; k0 < CDIM; k0 += 64) {
        #pragma unroll
        for (int i = 0; i < 32; ++i) wvB[i] = W1[(k0 + 32 + i) * CDIM + t];
        #pragma unroll
        for (int i = 0; i < 8; ++i) {
            const float4 x = sv4[(k0 >> 2) + i];
            hsum = fmaf(x.x, wvA[4 * i + 0], hsum);
            hsum = fmaf(x.y, wvA[4 * i + 1], hsum);
            hsum = fmaf(x.z, wvA[4 * i + 2], hsum);
            hsum = fmaf(x.w, wvA[4 * i + 3], hsum);
        }
        if (k0 + 64 < CDIM) {
            #pragma unroll
            for (int i = 0; i < 32; ++i) wvA[i] = W1[(k0 + 64 + i) * CDIM + t];
        }
        #pragma unroll
        for (int i = 0; i < 8; ++i) {
            const float4 x = sv4[(k0 >> 2) + 8 + i];
            hsum = fmaf(x.x, wvB[4 * i + 0], hsum);
            hsum = fmaf(x.y, wvB[4 * i + 1], hsum);
            hsum = fmaf(x.z, wvB[4 * i + 2], hsum);
            hsum = fmaf(x.w, wvB[4 * i + 3], hsum);
        }
    }
    s_hid[t] = fmaxf(hsum, 0.f);
    __syncthreads();

    const int g  = t >> 4;
    const int ln = t & 15;
    const int nOut = isDet ? 15 : 43;
    const int nrep = isDet ? 1 : 3;
    for (int rep = 0; rep < nrep; ++rep) {
        const int o = g + rep * 16;
        if (o < nOut) {
            const float* Wp; int stride, oo, ooff; float bias;
            if (isDet) {
                if (o < 4) { Wp = Wcd; stride = 4;  oo = o;     ooff = pt * 4 + oo;         bias = bcd[oo]; }
                else       { Wp = Wod; stride = 11; oo = o - 4; ooff = 3600 + pt * 11 + oo; bias = bod[oo] + detfull[pt * 11 + oo]; }
            } else {
                if (o < 3) { Wp = Wcm; stride = 3;  oo = o;     ooff = 13500 + m * 3 + oo;  bias = bcm[oo]; }
                else       { Wp = Wom; stride = 40; oo = o - 3; ooff = 13800 + m * 40 + oo; bias = bom[oo] + mapanch[m * 40 + oo]; }
            }
            float wv[16], xv[16];
            #pragma unroll
            for (int kk = 0; kk < 16; ++kk) wv[kk] = Wp[(ln + kk * 16) * stride + oo];
            #pragma unroll
            for (int kk = 0; kk < 16; ++kk) xv[kk] = s_hid[ln + kk * 16];
            float sp = 0.f;
            #pragma unroll
            for (int kk = 0; kk < 16; ++kk) sp = fmaf(xv[kk], wv[kk], sp);
            #pragma unroll
            for (int off = 1; off < 16; off <<= 1) sp += __shfl_xor(sp, off, 64);
            if (ln == 0) out[ooff] = sp + bias;
        }
    }
}

extern "C" void kernel_launch(void* const* d_in, const int* in_sizes, int n_in,
                              void* d_out, int out_size, void* d_ws, size_t ws_size,
                              hipStream_t stream) {
    const float* p2      = (const float*)d_in[0];
    const float* p3      = (const float*)d_in[1];
    const float* p4      = (const float*)d_in[2];
    const float* p5      = (const float*)d_in[3];
    const float* Kin     = (const float*)d_in[4];
    const float* Ein     = (const float*)d_in[5];
    const float* det3d   = (const float*)d_in[6];
    const float* detfull = (const float*)d_in[7];
    const float* mapanch = (const float*)d_in[8];
    const float* W1d     = (const float*)d_in[9];
    const float* b1d     = (const float*)d_in[10];
    const float* Wcd     = (const float*)d_in[11];
    const float* bcd     = (const float*)d_in[12];
    const float* Wod     = (const float*)d_in[13];
    const float* bod     = (const float*)d_in[14];
    const float* W1m     = (const float*)d_in[15];
    const float* b1m     = (const float*)d_in[16];
    const float* Wcm     = (const float*)d_in[17];
    const float* bcm     = (const float*)d_in[18];
    const float* Wom     = (const float*)d_in[19];
    const float* bom     = (const float*)d_in[20];
    float* out = (float*)d_out;
    u16* wsb = (u16*)d_ws;                     // packed bf16 features
    float* accw = (float*)d_ws + ACCF;         // level-0 partial acc

    k1_pack_p2<<<3070, 256, 0, stream>>>(
        p2, p3, p4, p5, Kin, Ein, det3d, mapanch, wsb, accw);

    k2_gather_mlp<<<NBLK, 256, 0, stream>>>(
        wsb, accw, Kin, Ein, det3d, detfull, mapanch,
        W1d, b1d, Wcd, bcd, Wod, bod, W1m, b1m, Wcm, bcm, Wom, bom, out);
}

// Round 16
// 44.538 us; speedup vs baseline: 7.6654x; 1.1455x over previous
//
#include <hip/hip_runtime.h>

#define CDIM 256
#define NDET 900
#define NMAP 100
#define NPTS 20
#define NBLK (NDET + NMAP)

using u16 = unsigned short;

// packed bf16 layouts in ws ([cam][px][C], ushort units)
#define U4OFF 7372800    // after p3T (6*4800*256)
#define U5OFF 9216000    // after p4T (6*1200*256)
#define ACC6F 4838400    // float index right after packed u16 region; acc6: [6][1000][256]
#define C3STR 1228800    // 4800*256
#define C4STR 307200     // 1200*256
#define C5STR 76800      // 300*256

__device__ __forceinline__ u16 f2bf(float f) {
    union { float f; unsigned int i; } v; v.f = f;
    return (u16)((v.i + 0x7FFFu + ((v.i >> 16) & 1u)) >> 16);
}
__device__ __forceinline__ float bf2f(u16 u) {
    union { unsigned int i; float f; } v; v.i = ((unsigned int)u) << 16; return v.f;
}

// ---------- K1: pack (blocks 0..2069) + per-(pt,cam) level-0 gather (2070..8069) ----------
__global__ __launch_bounds__(256, 4) void k1_pack_p2(
    const float* __restrict__ p2, const float* __restrict__ p3,
    const float* __restrict__ p4, const float* __restrict__ p5,
    const float* __restrict__ Kin, const float* __restrict__ Ein,
    const float* __restrict__ det3d, const float* __restrict__ mapanch,
    u16* __restrict__ wsb, float* __restrict__ acc6)
{
    const int b = blockIdx.x;
    const int t = threadIdx.x;

    __shared__ float s_tile[64][65];

    if (b < 1800) {
        // ---- p3 transpose tile: 64 px x 64 ch, coalesced read AND write ----
        const int cam = b / 300;
        const int rem = b % 300;
        const int pxT = rem >> 2, chT = rem & 3;
        const int lane = t & 63, wv = t >> 6;
        #pragma unroll
        for (int cc = 0; cc < 16; ++cc) {
            const int chl = wv * 16 + cc;
            s_tile[chl][lane] = p3[(cam * CDIM + chT * 64 + chl) * 4800 + pxT * 64 + lane];
        }
        __syncthreads();
        #pragma unroll
        for (int pp = 0; pp < 16; ++pp) {
            const int pxl = wv * 16 + pp;
            wsb[(cam * 4800 + pxT * 64 + pxl) * CDIM + chT * 64 + lane] = f2bf(s_tile[lane][pxl]);
        }
        return;
    }
    if (b < 1980) {
        const int id = b - 1800;
        const int cam = id / 30, h = id % 30;
        const float4* __restrict__ src = (const float4*)(p4 + ((cam * CDIM + t) * 30 + h) * 40);
        u16* __restrict__ dst = wsb + U4OFF + ((cam * 30 + h) * 40) * CDIM + t;
        #pragma unroll
        for (int w4 = 0; w4 < 10; ++w4) {
            const float4 v = src[w4];
            dst[(w4 * 4 + 0) * CDIM] = f2bf(v.x);
            dst[(w4 * 4 + 1) * CDIM] = f2bf(v.y);
            dst[(w4 * 4 + 2) * CDIM] = f2bf(v.z);
            dst[(w4 * 4 + 3) * CDIM] = f2bf(v.w);
        }
        return;
    }
    if (b < 2070) {
        const int id = b - 1980;
        const int cam = id / 15, h = id % 15;
        const float4* __restrict__ src = (const float4*)(p5 + ((cam * CDIM + t) * 15 + h) * 20);
        u16* __restrict__ dst = wsb + U5OFF + ((cam * 15 + h) * 20) * CDIM + t;
        #pragma unroll
        for (int w4 = 0; w4 < 5; ++w4) {
            const float4 v = src[w4];
            dst[(w4 * 4 + 0) * CDIM] = f2bf(v.x);
            dst[(w4 * 4 + 1) * CDIM] = f2bf(v.y);
            dst[(w4 * 4 + 2) * CDIM] = f2bf(v.z);
            dst[(w4 * 4 + 3) * CDIM] = f2bf(v.w);
        }
        return;
    }

    // ---- level-0 (p2) gather: one (pt, cam) tile per block ----
    const int id = b - 2070;          // 0..5999
    const int cam = id / 1000;        // 0..5 (cam-major: same-cam blocks cluster)
    const int pt = id % 1000;
    const bool isDet = (pt < NDET);
    const int m = pt - NDET;

    // redundant per-thread scalar setup (all L1-hot, no LDS/sync needed)
    float h0, h1, h2;
    if (isDet) {
        h0 = det3d[pt * 3 + 0];
        h1 = det3d[pt * 3 + 1];
        h2 = det3d[pt * 3 + 2];
    } else {
        float cx = 0.f, cy = 0.f;
        #pragma unroll
        for (int j = 0; j < NPTS; ++j) {
            cx += mapanch[(m * NPTS + j) * 2 + 0];
            cy += mapanch[(m * NPTS + j) * 2 + 1];
        }
        h0 = cx / (float)NPTS; h1 = cy / (float)NPTS; h2 = 0.f;
    }
    float pc[3];
    #pragma unroll
    for (int i = 0; i < 3; ++i) {
        pc[i] = Ein[cam * 16 + i * 4 + 0] * h0
              + Ein[cam * 16 + i * 4 + 1] * h1
              + Ein[cam * 16 + i * 4 + 2] * h2
              + Ein[cam * 16 + i * 4 + 3] * 1.f;
    }
    const float q0 = Kin[cam*9+0]*pc[0] + Kin[cam*9+1]*pc[1] + Kin[cam*9+2]*pc[2];
    const float q1 = Kin[cam*9+3]*pc[0] + Kin[cam*9+4]*pc[1] + Kin[cam*9+5]*pc[2];
    const float q2 = Kin[cam*9+6]*pc[0] + Kin[cam*9+7]*pc[1] + Kin[cam*9+8]*pc[2];
    const float depth = q2;
    const float u = q0 / (depth + 1e-6f);
    const float v = q1 / (depth + 1e-6f);
    const bool valid = (depth > 0.1f);
    const float gx = u / 640.0f * 2.0f - 1.0f;
    const float gy = v / 480.0f * 2.0f - 1.0f;
    const int H = 120, W = 160;
    const float x = (gx + 1.f) * (W * 0.5f) - 0.5f;
    const float y = (gy + 1.f) * (H * 0.5f) - 0.5f;
    const float x0f = floorf(x), y0f = floorf(y);
    const float wx1 = x - x0f, wx0 = 1.f - wx1;
    const float wy1 = y - y0f, wy0 = 1.f - wy1;
    const float x1f = x0f + 1.f, y1f = y0f + 1.f;
    const bool bx0 = (x0f >= 0.f) && (x0f <= (float)(W - 1));
    const bool bx1 = (x1f >= 0.f) && (x1f <= (float)(W - 1));
    const bool by0 = (y0f >= 0.f) && (y0f <= (float)(H - 1));
    const bool by1 = (y1f >= 0.f) && (y1f <= (float)(H - 1));
    const int xc0 = (int)fminf(fmaxf(x0f, 0.f), (float)(W - 1));
    const int xc1 = (int)fminf(fmaxf(x1f, 0.f), (float)(W - 1));
    const int yc0 = (int)fminf(fmaxf(y0f, 0.f), (float)(H - 1));
    const int yc1 = (int)fminf(fmaxf(y1f, 0.f), (float)(H - 1));
    const float w0 = (bx0 && by0) ? wx0 * wy0 : 0.f;
    const float w1 = (bx1 && by0) ? wx1 * wy0 : 0.f;
    const float w2 = (bx0 && by1) ? wx0 * wy1 : 0.f;
    const float w3 = (bx1 && by1) ? wx1 * wy1 : 0.f;

    float res = 0.f;
    if (valid && ((w0 + w1 + w2 + w3) != 0.f)) {   // block-uniform branch
        const int base = cam * CDIM * H * W + t * (H * W);
        const float v0 = p2[base + yc0 * W + xc0];
        const float v1 = p2[base + yc0 * W + xc1];
        const float v2 = p2[base + yc1 * W + xc0];
        const float v3 = p2[base + yc1 * W + xc1];
        res = w0 * v0 + w1 * v1 + w2 * v2 + w3 * v3;
    }
    acc6[(cam * 1000 + pt) * CDIM + t] = res;
}

// ---------- K2: sum acc6 + levels 1-3 coalesced bf16 gather + MLP + heads ----------
__global__ __launch_bounds__(256, 4) void k2_gather_mlp(
    const u16* __restrict__ wsb, const float* __restrict__ acc6,
    const float* __restrict__ Kin, const float* __restrict__ Ein,
    const float* __restrict__ det3d, const float* __restrict__ detfull,
    const float* __restrict__ mapanch,
    const float* __restrict__ W1d, const float* __restrict__ b1d,
    const float* __restrict__ Wcd, const float* __restrict__ bcd,
    const float* __restrict__ Wod, const float* __restrict__ bod,
    const float* __restrict__ W1m, const float* __restrict__ b1m,
    const float* __restrict__ Wcm, const float* __restrict__ bcm,
    const float* __restrict__ Wom, const float* __restrict__ bom,
    float* __restrict__ out)
{
    const int pt = blockIdx.x;
    const int t  = threadIdx.x;
    const bool isDet = (pt < NDET);
    const int m = pt - NDET;

    __shared__ int   s_off[19][4];
    __shared__ float s_w[19][4];
    __shared__ int   s_list[24];
    __shared__ int   s_n;
    __shared__ float s_vec[CDIM];
    __shared__ float s_hid[CDIM];

    // level-0 partial: fixed-order sum of the 6 camera partials (deterministic)
    float a0 = acc6[(0 * 1000 + pt) * CDIM + t];
    float a1 = acc6[(1 * 1000 + pt) * CDIM + t];
    float a2 = acc6[(2 * 1000 + pt) * CDIM + t];
    float a3 = acc6[(3 * 1000 + pt) * CDIM + t];
    float a4 = acc6[(4 * 1000 + pt) * CDIM + t];
    float a5 = acc6[(5 * 1000 + pt) * CDIM + t];
    float acc = ((((a0 + a1) + a2) + a3) + a4) + a5;

    if (t < 19) {
        float h0, h1, h2;
        if (isDet) {
            h0 = det3d[pt * 3 + 0];
            h1 = det3d[pt * 3 + 1];
            h2 = det3d[pt * 3 + 2];
        } else {
            float cx = 0.f, cy = 0.f;
            #pragma unroll
            for (int j = 0; j < NPTS; ++j) {
                cx += mapanch[(m * NPTS + j) * 2 + 0];
                cy += mapanch[(m * NPTS + j) * 2 + 1];
            }
            h0 = cx / (float)NPTS; h1 = cy / (float)NPTS; h2 = 0.f;
        }
        bool pred = false;
        if (t < 18) {
            const int cam = t / 3, l = 1 + (t % 3);
            float pc[3];
            #pragma unroll
            for (int i = 0; i < 3; ++i) {
                pc[i] = Ein[cam * 16 + i * 4 + 0] * h0
                      + Ein[cam * 16 + i * 4 + 1] * h1
                      + Ein[cam * 16 + i * 4 + 2] * h2
                      + Ein[cam * 16 + i * 4 + 3] * 1.f;
            }
            const float q0 = Kin[cam*9+0]*pc[0] + Kin[cam*9+1]*pc[1] + Kin[cam*9+2]*pc[2];
            const float q1 = Kin[cam*9+3]*pc[0] + Kin[cam*9+4]*pc[1] + Kin[cam*9+5]*pc[2];
            const float q2 = Kin[cam*9+6]*pc[0] + Kin[cam*9+7]*pc[1] + Kin[cam*9+8]*pc[2];
            const float depth = q2;
            const float u = q0 / (depth + 1e-6f);
            const float v = q1 / (depth + 1e-6f);
            const bool valid = (depth > 0.1f);
            const float gx = u / 640.0f * 2.0f - 1.0f;
            const float gy = v / 480.0f * 2.0f - 1.0f;
            const int Hs[4] = {120, 60, 30, 15};
            const int Ws[4] = {160, 80, 40, 20};
            const int H = Hs[l], W = Ws[l];
            const float x = (gx + 1.f) * (W * 0.5f) - 0.5f;
            const float y = (gy + 1.f) * (H * 0.5f) - 0.5f;
            const float x0f = floorf(x), y0f = floorf(y);
            const float wx1 = x - x0f, wx0 = 1.f - wx1;
            const float wy1 = y - y0f, wy0 = 1.f - wy1;
            const float x1f = x0f + 1.f, y1f = y0f + 1.f;
            const bool bx0 = (x0f >= 0.f) && (x0f <= (float)(W - 1));
            const bool bx1 = (x1f >= 0.f) && (x1f <= (float)(W - 1));
            const bool by0 = (y0f >= 0.f) && (y0f <= (float)(H - 1));
            const bool by1 = (y1f >= 0.f) && (y1f <= (float)(H - 1));
            const int xc0 = (int)fminf(fmaxf(x0f, 0.f), (float)(W - 1));
            const int xc1 = (int)fminf(fmaxf(x1f, 0.f), (float)(W - 1));
            const int yc0 = (int)fminf(fmaxf(y0f, 0.f), (float)(H - 1));
            const int yc1 = (int)fminf(fmaxf(y1f, 0.f), (float)(H - 1));
            const int pb = (l == 1) ? cam * C3STR
                         : (l == 2) ? (U4OFF + cam * C4STR)
                                    : (U5OFF + cam * C5STR);
            s_off[t][0] = pb + (yc0 * W + xc0) * CDIM;
            s_off[t][1] = pb + (yc0 * W + xc1) * CDIM;
            s_off[t][2] = pb + (yc1 * W + xc0) * CDIM;
            s_off[t][3] = pb + (yc1 * W + xc1) * CDIM;
            const float w0 = (bx0 && by0) ? wx0 * wy0 : 0.f;
            const float w1 = (bx1 && by0) ? wx1 * wy0 : 0.f;
            const float w2 = (bx0 && by1) ? wx0 * wy1 : 0.f;
            const float w3 = (bx1 && by1) ? wx1 * wy1 : 0.f;
            s_w[t][0] = w0; s_w[t][1] = w1; s_w[t][2] = w2; s_w[t][3] = w3;
            pred = valid && ((w0 + w1 + w2 + w3) != 0.f);
        } else {
            s_off[18][0] = 0; s_off[18][1] = 0; s_off[18][2] = 0; s_off[18][3] = 0;
            s_w[18][0] = 0.f; s_w[18][1] = 0.f; s_w[18][2] = 0.f; s_w[18][3] = 0.f;
        }
        const unsigned long long mask = __ballot(pred);
        const int n = __popcll(mask);
        const int rank = __popcll(mask & ((1ull << t) - 1ull));
        if (pred) s_list[rank] = t;
        const int npad = (n + 7) & ~7;
        if (t < 8 && (n + t) < npad) s_list[n + t] = 18;
        if (t == 0) s_n = npad;
    }
    __syncthreads();

    const int npad = s_n;
    for (int base = 0; base < npad; base += 8) {
        float v[8][4];
        int tj[8];
        #pragma unroll
        for (int j = 0; j < 8; ++j) {
            const int tt = s_list[base + j];
            tj[j] = tt;
            v[j][0] = bf2f(wsb[s_off[tt][0] + t]);
            v[j][1] = bf2f(wsb[s_off[tt][1] + t]);
            v[j][2] = bf2f(wsb[s_off[tt][2] + t]);
            v[j][3] = bf2f(wsb[s_off[tt][3] + t]);
        }
        #pragma unroll
        for (int j = 0; j < 8; ++j) {
            const int tt = tj[j];
            acc += s_w[tt][0] * v[j][0] + s_w[tt][1] * v[j][1]
                 + s_w[tt][2] * v[j][2] + s_w[tt][3] * v[j][3];
        }
    }
    const float agg = (acc * 0.25f) / 6.0f;

    s_vec[t] = agg;
    __syncthreads();

    const float* __restrict__ W1 = isDet ? W1d : W1m;
    const float* __restrict__ b1 = isDet ? b1d : b1m;
    float hsum = b1[t];
    const float4* sv4 = (const float4*)s_vec;
    float wvA[32], wvB[32];
    #pragma unroll
    for (int i = 0; i < 32; ++i) wvA[i] = W1[i * CDIM + t];
    #pragma unroll
    for (int k0 = 0; k0 < CDIM; k0 += 64) {
        #pragma unroll
        for (int i = 0; i < 32; ++i) wvB[i] = W1[(k0 + 32 + i) * CDIM + t];
        #pragma unroll
        for (int i = 0; i < 8; ++i) {
            const float4 x = sv4[(k0 >> 2) + i];
            hsum = fmaf(x.x, wvA[4 * i + 0], hsum);
            hsum = fmaf(x.y, wvA[4 * i + 1], hsum);
            hsum = fmaf(x.z, wvA[4 * i + 2], hsum);
            hsum = fmaf(x.w, wvA[4 * i + 3], hsum);
        }
        if (k0 + 64 < CDIM) {
            #pragma unroll
            for (int i = 0; i < 32; ++i) wvA[i] = W1[(k0 + 64 + i) * CDIM + t];
        }
        #pragma unroll
        for (int i = 0; i < 8; ++i) {
            const float4 x = sv4[(k0 >> 2) + 8 + i];
            hsum = fmaf(x.x, wvB[4 * i + 0], hsum);
            hsum = fmaf(x.y, wvB[4 * i + 1], hsum);
            hsum = fmaf(x.z, wvB[4 * i + 2], hsum);
            hsum = fmaf(x.w, wvB[4 * i + 3], hsum);
        }
    }
    s_hid[t] = fmaxf(hsum, 0.f);
    __syncthreads();

    const int g  = t >> 4;
    const int ln = t & 15;
    const int nOut = isDet ? 15 : 43;
    const int nrep = isDet ? 1 : 3;
    for (int rep = 0; rep < nrep; ++rep) {
        const int o = g + rep * 16;
        if (o < nOut) {
            const float* Wp; int stride, oo, ooff; float bias;
            if (isDet) {
                if (o < 4) { Wp = Wcd; stride = 4;  oo = o;     ooff = pt * 4 + oo;         bias = bcd[oo]; }
                else       { Wp = Wod; stride = 11; oo = o - 4; ooff = 3600 + pt * 11 + oo; bias = bod[oo] + detfull[pt * 11 + oo]; }
            } else {
                if (o < 3) { Wp = Wcm; stride = 3;  oo = o;     ooff = 13500 + m * 3 + oo;  bias = bcm[oo]; }
                else       { Wp = Wom; stride = 40; oo = o - 3; ooff = 13800 + m * 40 + oo; bias = bom[oo] + mapanch[m * 40 + oo]; }
            }
            float wv[16], xv[16];
            #pragma unroll
            for (int kk = 0; kk < 16; ++kk) wv[kk] = Wp[(ln + kk * 16) * stride + oo];
            #pragma unroll
            for (int kk = 0; kk < 16; ++kk) xv[kk] = s_hid[ln + kk * 16];
            float sp = 0.f;
            #pragma unroll
            for (int kk = 0; kk < 16; ++kk) sp = fmaf(xv[kk], wv[kk], sp);
            #pragma unroll
            for (int off = 1; off < 16; off <<= 1) sp += __shfl_xor(sp, off, 64);
            if (ln == 0) out[ooff] = sp + bias;
        }
    }
}

extern "C" void kernel_launch(void* const* d_in, const int* in_sizes, int n_in,
                              void* d_out, int out_size, void* d_ws, size_t ws_size,
                              hipStream_t stream) {
    const float* p2      = (const float*)d_in[0];
    const float* p3      = (const float*)d_in[1];
    const float* p4      = (const float*)d_in[2];
    const float* p5      = (const float*)d_in[3];
    const float* Kin     = (const float*)d_in[4];
    const float* Ein     = (const float*)d_in[5];
    const float* det3d   = (const float*)d_in[6];
    const float* detfull = (const float*)d_in[7];
    const float* mapanch = (const float*)d_in[8];
    const float* W1d     = (const float*)d_in[9];
    const float* b1d     = (const float*)d_in[10];
    const float* Wcd     = (const float*)d_in[11];
    const float* bcd     = (const float*)d_in[12];
    const float* Wod     = (const float*)d_in[13];
    const float* bod     = (const float*)d_in[14];
    const float* W1m     = (const float*)d_in[15];
    const float* b1m     = (const float*)d_in[16];
    const float* Wcm     = (const float*)d_in[17];
    const float* bcm     = (const float*)d_in[18];
    const float* Wom     = (const float*)d_in[19];
    const float* bom     = (const float*)d_in[20];
    float* out = (float*)d_out;
    u16* wsb = (u16*)d_ws;                     // packed bf16 features
    float* acc6 = (float*)d_ws + ACC6F;        // [6][1000][256] level-0 partials

    k1_pack_p2<<<8070, 256, 0, stream>>>(
        p2, p3, p4, p5, Kin, Ein, det3d, mapanch, wsb, acc6);

    k2_gather_mlp<<<NBLK, 256, 0, stream>>>(
        wsb, acc6, Kin, Ein, det3d, detfull, mapanch,
        W1d, b1d, Wcd, bcd, Wod, bod, W1m, b1m, Wcm, bcm, Wom, bom, out);
}